// Round 1
// baseline (421.098 us; speedup 1.0000x reference)
//
#include <hip/hip_runtime.h>
#include <hip/hip_bf16.h>
#include <math.h>

#define L 1024
#define NB 2
#define DM 256
#define DI 512
#define DS 16
#define DR 16
#define NC 32
#define CL 32   // L / NC

__device__ __forceinline__ float sigmoidf_(float x){ return 1.f/(1.f+__expf(-x)); }

// ---------- transpose in: x (b,c,hw) -> u (b,hw,c)
__global__ __launch_bounds__(256) void k_transpose_in(const float* __restrict__ x, float* __restrict__ u){
  int g = blockIdx.x*256 + threadIdx.x;       // c fastest
  int c = g & 255; int l = (g >> 8) & 1023; int b = g >> 18;
  u[g] = x[((size_t)(b*DM + c))*L + l];
}

// ---------- channel flip: out[..., c] = in[..., 255-c]
__global__ __launch_bounds__(256) void k_flip(const float* __restrict__ in, float* __restrict__ out){
  int g = blockIdx.x*256 + threadIdx.x;
  int c = g & 255;
  out[g] = in[(g - c) + (255 - c)];
}

// ---------- final: out (b,c,hw) = flip_c(xt (b,hw,c))
__global__ __launch_bounds__(256) void k_final(const float* __restrict__ xt, float* __restrict__ out){
  int g = blockIdx.x*256 + threadIdx.x;       // over b,c,l with l fastest
  int l = g & 1023; int c = (g >> 10) & 255; int b = g >> 18;
  out[g] = xt[((size_t)(b*L + l))*DM + (255 - c)];
}

// ---------- generic tiled f32 GEMM: C[M,N] = A[M,K] @ W[K,N] (+bias)
// BM=BN=64, BK=16, 256 threads, 4x4 per thread. M % 64 == 0, K % 16 == 0. N guarded.
__global__ __launch_bounds__(256) void k_gemm(const float* __restrict__ A, const float* __restrict__ W,
    const float* __restrict__ bias, float* __restrict__ C, int M, int N, int K){
  __shared__ float As[16][65];
  __shared__ float Bs[16][65];
  int tid = threadIdx.x;
  int bn = blockIdx.x * 64;
  int bm = blockIdx.y * 64;
  int tx = tid & 15, ty = tid >> 4;
  int ar = tid >> 2, ac = (tid & 3) << 2;   // A tile: 64 rows x 16 cols
  int wr = tid >> 4, wc = (tid & 15) << 2;  // W tile: 16 rows x 64 cols
  float acc[4][4] = {};
  for (int k0 = 0; k0 < K; k0 += 16){
    float4 av = *(const float4*)(A + (size_t)(bm + ar)*K + k0 + ac);
    As[ac+0][ar]=av.x; As[ac+1][ar]=av.y; As[ac+2][ar]=av.z; As[ac+3][ar]=av.w;
    int ncol = bn + wc;
    if (ncol + 3 < N){
      float4 wv = *(const float4*)(W + (size_t)(k0 + wr)*N + ncol);
      Bs[wr][wc+0]=wv.x; Bs[wr][wc+1]=wv.y; Bs[wr][wc+2]=wv.z; Bs[wr][wc+3]=wv.w;
    } else {
      #pragma unroll
      for (int j=0;j<4;++j){ int n = ncol+j; Bs[wr][wc+j] = (n < N) ? W[(size_t)(k0+wr)*N + n] : 0.f; }
    }
    __syncthreads();
    #pragma unroll
    for (int k=0;k<16;++k){
      float a0=As[k][ty*4+0], a1=As[k][ty*4+1], a2=As[k][ty*4+2], a3=As[k][ty*4+3];
      float b0=Bs[k][tx*4+0], b1=Bs[k][tx*4+1], b2=Bs[k][tx*4+2], b3=Bs[k][tx*4+3];
      acc[0][0]=fmaf(a0,b0,acc[0][0]); acc[0][1]=fmaf(a0,b1,acc[0][1]); acc[0][2]=fmaf(a0,b2,acc[0][2]); acc[0][3]=fmaf(a0,b3,acc[0][3]);
      acc[1][0]=fmaf(a1,b0,acc[1][0]); acc[1][1]=fmaf(a1,b1,acc[1][1]); acc[1][2]=fmaf(a1,b2,acc[1][2]); acc[1][3]=fmaf(a1,b3,acc[1][3]);
      acc[2][0]=fmaf(a2,b0,acc[2][0]); acc[2][1]=fmaf(a2,b1,acc[2][1]); acc[2][2]=fmaf(a2,b2,acc[2][2]); acc[2][3]=fmaf(a2,b3,acc[2][3]);
      acc[3][0]=fmaf(a3,b0,acc[3][0]); acc[3][1]=fmaf(a3,b1,acc[3][1]); acc[3][2]=fmaf(a3,b2,acc[3][2]); acc[3][3]=fmaf(a3,b3,acc[3][3]);
    }
    __syncthreads();
  }
  #pragma unroll
  for (int i=0;i<4;++i){
    int m = bm + ty*4 + i;
    #pragma unroll
    for (int j=0;j<4;++j){
      int n = bn + tx*4 + j;
      if (n < N) C[(size_t)m*N + n] = acc[i][j] + (bias ? bias[n] : 0.f);
    }
  }
}

// ---------- depthwise causal conv (D_CONV=4) + SiLU. xr is (b,L,1024); first 512 chans are xs.
__global__ __launch_bounds__(256) void k_conv_silu(const float* __restrict__ xr, const float* __restrict__ cw,
    const float* __restrict__ cb, float* __restrict__ xsc){
  int g = blockIdx.x*256 + threadIdx.x;   // d fastest, then l, then b
  int d = g & 511; int l = (g >> 9) & 1023; int b = g >> 19;
  float acc = cb[d];
  const float* w = cw + d*4;
  #pragma unroll
  for (int k=0;k<4;++k){
    int j = l + k - 3;
    if (j >= 0) acc = fmaf(w[k], xr[((size_t)(b*L + j))*(2*DI) + d], acc);
  }
  xsc[g] = acc * sigmoidf_(acc);
}

// ---------- delta = softplus(x_dbl[:, :16] @ dt_w + dt_b)
__global__ __launch_bounds__(256) void k_dt_softplus(const float* __restrict__ xdbl, const float* __restrict__ dtw,
    const float* __restrict__ dtb, float* __restrict__ delta){
  int g = blockIdx.x*256 + threadIdx.x;   // n fastest; rows = NB*L
  int n = g & 511; int m = g >> 9;
  float acc = dtb[n];
  const float* xp = xdbl + (size_t)m*48;
  #pragma unroll
  for (int k=0;k<16;++k) acc = fmaf(xp[k], dtw[k*DI + n], acc);
  delta[g] = fmaxf(acc, 0.f) + log1pf(__expf(-fabsf(acc)));
}

// ---------- scan phase A: per-chunk local scan from h=0; store h_end and sum(delta)
__global__ __launch_bounds__(256) void k_scan_partial(const float* __restrict__ delta, const float* __restrict__ xsc,
    const float* __restrict__ xdbl, const float* __restrict__ A_log,
    float* __restrict__ hend, float* __restrict__ Ssum){
  int g = blockIdx.x*256 + threadIdx.x;   // d fastest, then chunk, then b
  int d = g & 511; int bc = g >> 9;       // bc = b*NC + c
  int c = bc & (NC-1); int b = bc >> 5;
  float A[DS];
  #pragma unroll
  for (int n=0;n<DS;++n) A[n] = -__expf(A_log[d*DS + n]);
  float h[DS];
  #pragma unroll
  for (int n=0;n<DS;++n) h[n] = 0.f;
  float S = 0.f;
  int l0 = c*CL;
  for (int t=0;t<CL;++t){
    size_t ix = (size_t)(b*L + l0 + t);
    float dlt = delta[ix*DI + d];
    float xv  = xsc[ix*DI + d];
    S += dlt;
    float dx = dlt * xv;
    const float* bp = xdbl + ix*48 + DR;
    #pragma unroll
    for (int n=0;n<DS;++n){
      float dA = __expf(dlt * A[n]);
      h[n] = fmaf(dA, h[n], dx * bp[n]);
    }
  }
  #pragma unroll
  for (int n=0;n<DS;++n) hend[((size_t)bc*DS + n)*DI + d] = h[n];
  Ssum[(size_t)bc*DI + d] = S;
}

// ---------- scan phase B: sequentially combine chunk states per (b,d)
__global__ __launch_bounds__(256) void k_scan_combine(const float* __restrict__ hend, const float* __restrict__ Ssum,
    const float* __restrict__ A_log, float* __restrict__ hinit){
  int g = blockIdx.x*256 + threadIdx.x;   // 1024 threads: d fastest, then b
  int d = g & 511; int b = g >> 9;
  float A[DS];
  #pragma unroll
  for (int n=0;n<DS;++n) A[n] = -__expf(A_log[d*DS + n]);
  float h[DS];
  #pragma unroll
  for (int n=0;n<DS;++n) h[n] = 0.f;
  for (int c=0;c<NC;++c){
    int bc = b*NC + c;
    #pragma unroll
    for (int n=0;n<DS;++n) hinit[((size_t)bc*DS + n)*DI + d] = h[n];
    float S = Ssum[(size_t)bc*DI + d];
    #pragma unroll
    for (int n=0;n<DS;++n){
      float dec = __expf(A[n]*S);
      h[n] = fmaf(dec, h[n], hend[((size_t)bc*DS + n)*DI + d]);
    }
  }
}

// ---------- scan phase C: re-run chunk from correct h_init; fuse D-skip and SiLU gating
__global__ __launch_bounds__(256) void k_scan_final(const float* __restrict__ delta, const float* __restrict__ xsc,
    const float* __restrict__ xdbl, const float* __restrict__ xr, const float* __restrict__ A_log,
    const float* __restrict__ Dp, const float* __restrict__ hinit, float* __restrict__ yg){
  int g = blockIdx.x*256 + threadIdx.x;
  int d = g & 511; int bc = g >> 9;
  int c = bc & (NC-1); int b = bc >> 5;
  float A[DS];
  #pragma unroll
  for (int n=0;n<DS;++n) A[n] = -__expf(A_log[d*DS + n]);
  float h[DS];
  #pragma unroll
  for (int n=0;n<DS;++n) h[n] = hinit[((size_t)bc*DS + n)*DI + d];
  float Dv = Dp[d];
  int l0 = c*CL;
  for (int t=0;t<CL;++t){
    size_t ix = (size_t)(b*L + l0 + t);
    float dlt = delta[ix*DI + d];
    float xv  = xsc[ix*DI + d];
    float res = xr[ix*(2*DI) + DI + d];
    float dx = dlt * xv;
    const float* bp = xdbl + ix*48 + DR;
    const float* cp = xdbl + ix*48 + DR + DS;
    float y = 0.f;
    #pragma unroll
    for (int n=0;n<DS;++n){
      float dA = __expf(dlt * A[n]);
      h[n] = fmaf(dA, h[n], dx * bp[n]);
      y = fmaf(h[n], cp[n], y);
    }
    y = fmaf(xv, Dv, y);
    yg[ix*DI + d] = y * (res * sigmoidf_(res));
  }
}

// ---------- LayerNorm(mo) * w + b + residual
__global__ __launch_bounds__(256) void k_ln_add(const float* __restrict__ mo, const float* __restrict__ resid,
    const float* __restrict__ w, const float* __restrict__ bias, float* __restrict__ out){
  int row = blockIdx.x; int tid = threadIdx.x;
  float x = mo[(size_t)row*DM + tid];
  __shared__ float r1[256], r2[256];
  r1[tid] = x; r2[tid] = x*x;
  __syncthreads();
  for (int st=128; st>0; st>>=1){
    if (tid < st){ r1[tid]+=r1[tid+st]; r2[tid]+=r2[tid+st]; }
    __syncthreads();
  }
  float mu = r1[0] * (1.f/DM);
  float var = r2[0] * (1.f/DM) - mu*mu;
  float inv = rsqrtf(var + 1e-5f);
  out[(size_t)row*DM + tid] = resid[(size_t)row*DM + tid] + (x - mu)*inv*w[tid] + bias[tid];
}

static void run_block(const float* u, const float* inw, const float* inb, const float* cw, const float* cb,
                      const float* xpw, const float* dtw, const float* dtb, const float* Alog, const float* Dp,
                      const float* ow, const float* ob,
                      float* xr, float* xsc, float* xdbl, float* dlt, float* yg,
                      float* hend, float* hinit, float* Ssum, float* mo, hipStream_t stream){
  dim3 b256(256);
  k_gemm<<<dim3(16,32), b256, 0, stream>>>(u, inw, inb, xr, NB*L, 2*DI, DM);
  k_conv_silu<<<4096, b256, 0, stream>>>(xr, cw, cb, xsc);
  k_gemm<<<dim3(1,32), b256, 0, stream>>>(xsc, xpw, nullptr, xdbl, NB*L, DR + 2*DS, DI);
  k_dt_softplus<<<4096, b256, 0, stream>>>(xdbl, dtw, dtb, dlt);
  k_scan_partial<<<128, b256, 0, stream>>>(dlt, xsc, xdbl, Alog, hend, Ssum);
  k_scan_combine<<<4, b256, 0, stream>>>(hend, Ssum, Alog, hinit);
  k_scan_final<<<128, b256, 0, stream>>>(dlt, xsc, xdbl, xr, Alog, Dp, hinit, yg);
  k_gemm<<<dim3(4,32), b256, 0, stream>>>(yg, ow, ob, mo, NB*L, DM, DI);
}

extern "C" void kernel_launch(void* const* d_in, const int* in_sizes, int n_in,
                              void* d_out, int out_size, void* d_ws, size_t ws_size,
                              hipStream_t stream) {
  const float* x    = (const float*)d_in[0];
  const float* ln1w = (const float*)d_in[1];
  const float* ln1b = (const float*)d_in[2];
  const float* ln2w = (const float*)d_in[3];
  const float* ln2b = (const float*)d_in[4];

  const float* m1[11]; const float* m2[11];
  for (int i=0;i<11;++i){ m1[i] = (const float*)d_in[5+i]; m2[i] = (const float*)d_in[16+i]; }
  // order: in_w, in_b, conv_w, conv_b, xproj_w, dt_w, dt_b, A_log, D, out_w, out_b

  float* ws = (float*)d_ws;
  float* u0    = ws;               // 524288
  float* xr    = u0    + 524288;   // 2097152
  float* xsc   = xr    + 2097152;  // 1048576
  float* xdbl  = xsc   + 1048576;  // 98304
  float* dlt   = xdbl  + 98304;    // 1048576
  float* yg    = dlt   + 1048576;  // 1048576
  float* hend  = yg    + 1048576;  // 524288
  float* hinit = hend  + 524288;   // 524288
  float* Ssum  = hinit + 524288;   // 32768
  float* mo    = Ssum  + 32768;    // 524288
  float* xt1   = mo    + 524288;   // 524288
  float* u2    = xt1   + 524288;   // 524288
  float* xt3   = u2    + 524288;   // 524288

  dim3 b256(256);
  k_transpose_in<<<2048, b256, 0, stream>>>(x, u0);

  run_block(u0, m1[0], m1[1], m1[2], m1[3], m1[4], m1[5], m1[6], m1[7], m1[8], m1[9], m1[10],
            xr, xsc, xdbl, dlt, yg, hend, hinit, Ssum, mo, stream);
  k_ln_add<<<2048, b256, 0, stream>>>(mo, u0, ln1w, ln1b, xt1);

  k_flip<<<2048, b256, 0, stream>>>(xt1, u2);

  run_block(u2, m2[0], m2[1], m2[2], m2[3], m2[4], m2[5], m2[6], m2[7], m2[8], m2[9], m2[10],
            xr, xsc, xdbl, dlt, yg, hend, hinit, Ssum, mo, stream);
  k_ln_add<<<2048, b256, 0, stream>>>(mo, u2, ln2w, ln2b, xt3);

  k_final<<<2048, b256, 0, stream>>>(xt3, (float*)d_out);
}

// Round 2
// 170.058 us; speedup vs baseline: 2.4762x; 2.4762x over previous
//
#include <hip/hip_runtime.h>
#include <hip/hip_bf16.h>
#include <math.h>

#define L 1024
#define NB 2
#define DM 256
#define DI 512
#define DS 16
#define DR 16
#define NC 64
#define CL 16   // L / NC

typedef unsigned int u32;
typedef unsigned short ushortt;
typedef short s16x8 __attribute__((ext_vector_type(8)));
typedef float f32x4 __attribute__((ext_vector_type(4)));

__device__ __forceinline__ float sigmoidf_(float x){ return 1.f/(1.f+__expf(-x)); }

__device__ __forceinline__ unsigned short f2bf(float v){
  u32 x = __float_as_uint(v);
  u32 r = (x + 0x7fffu + ((x >> 16) & 1u)) >> 16;
  return (unsigned short)r;
}

__device__ __forceinline__ void gload_lds16(const void* g, void* l){
  __builtin_amdgcn_global_load_lds((const __attribute__((address_space(1))) u32*)g,
                                   (__attribute__((address_space(3))) u32*)l, 16, 0, 0);
}

// ---------- transpose in: x (b,c,hw) -> u (b,hw,c), fp32 + bf16 copies
__global__ __launch_bounds__(256) void k_transpose_in(const float* __restrict__ x,
    float* __restrict__ u, unsigned short* __restrict__ ub){
  int g = blockIdx.x*256 + threadIdx.x;       // c fastest
  int c = g & 255; int l = (g >> 8) & 1023; int b = g >> 18;
  float v = x[((size_t)(b*DM + c))*L + l];
  u[g] = v; ub[g] = f2bf(v);
}

// ---------- channel flip: out[..., c] = in[..., 255-c]; fp32 + bf16
__global__ __launch_bounds__(256) void k_flip(const float* __restrict__ in,
    float* __restrict__ out, unsigned short* __restrict__ outb){
  int g = blockIdx.x*256 + threadIdx.x;
  int c = g & 255;
  float v = in[(g - c) + (255 - c)];
  out[g] = v; outb[g] = f2bf(v);
}

// ---------- final: out (b,c,hw) = flip_c(xt (b,hw,c))
__global__ __launch_bounds__(256) void k_final(const float* __restrict__ xt, float* __restrict__ out){
  int g = blockIdx.x*256 + threadIdx.x;       // over b,c,l with l fastest
  int l = g & 1023; int c = (g >> 10) & 255; int b = g >> 18;
  out[g] = xt[((size_t)(b*L + l))*DM + (255 - c)];
}

// ---------- weight convert+transpose: Wt[n][k] (bf16) = W[k][n] (f32), n padded to Npad with 0
__global__ __launch_bounds__(256) void k_wconv(const float* __restrict__ W, unsigned short* __restrict__ Wt,
    int K, int N, int Npad){
  int g = blockIdx.x*256 + threadIdx.x;  // k fastest
  int k = g % K; int n = g / K;
  if (n >= Npad) return;
  float v = (n < N) ? W[(size_t)k*N + n] : 0.f;
  Wt[(size_t)n*K + k] = f2bf(v);
}

// ---------- MFMA bf16 GEMM: C[M][N] f32 = A[M][K]bf16 @ Wt[N][K]bf16^T (+bias)
// BM=BN=64, BK=64, 256 threads = 4 waves (2x2 of 32x32). K % 64 == 0, M % 64 == 0.
// LDS tiles [64 rows][64 k] bf16 with 16B-slot XOR swizzle: slot = kgrp ^ (row&7).
__global__ __launch_bounds__(256) void k_gemm_mfma(const unsigned short* __restrict__ A,
    const unsigned short* __restrict__ Wt, const float* __restrict__ bias,
    float* __restrict__ C, int M, int N, int K){
  __shared__ __align__(16) unsigned short As[64*64];
  __shared__ __align__(16) unsigned short Bs[64*64];
  int tid = threadIdx.x;
  int lane = tid & 63;
  int wid  = tid >> 6;
  int bm = blockIdx.y * 64, bn = blockIdx.x * 64;
  int wm = (wid >> 1) * 32, wn = (wid & 1) * 32;
  int lrow = lane & 15, lg = lane >> 4;
  int srow = tid >> 3;      // 0..31 (issue 0), +32 (issue 1)
  int ssl  = tid & 7;
  int sswz = ssl ^ (srow & 7);   // same for both issues (32 ≡ 0 mod 8)

  f32x4 acc[2][2] = {};

  for (int k0 = 0; k0 < K; k0 += 64){
    // stage A tile + B tile: pre-swizzled global source, linear LDS dest (lane-linear)
    #pragma unroll
    for (int i = 0; i < 2; ++i){
      int row = srow + i*32;
      gload_lds16(A  + (size_t)(bm + row)*K + k0 + sswz*8, &As[row*64 + ssl*8]);
      gload_lds16(Wt + (size_t)(bn + row)*K + k0 + sswz*8, &Bs[row*64 + ssl*8]);
    }
    __syncthreads();
    #pragma unroll
    for (int ks = 0; ks < 2; ++ks){
      int kg = ks*4 + lg;
      int swz = (kg ^ (lrow & 7)) << 3;
      s16x8 a[2], b[2];
      #pragma unroll
      for (int f = 0; f < 2; ++f){
        a[f] = *(const s16x8*)&As[(wm + f*16 + lrow)*64 + swz];
        b[f] = *(const s16x8*)&Bs[(wn + f*16 + lrow)*64 + swz];
      }
      #pragma unroll
      for (int i = 0; i < 2; ++i)
        #pragma unroll
        for (int j = 0; j < 2; ++j)
          acc[i][j] = __builtin_amdgcn_mfma_f32_16x16x32_bf16(a[i], b[j], acc[i][j], 0, 0, 0);
    }
    __syncthreads();
  }
  // epilogue: D[(lane>>4)*4 + r][lane&15] per 16x16 frag
  #pragma unroll
  for (int j = 0; j < 2; ++j){
    int col = bn + wn + j*16 + lrow;
    if (col < N){
      float bv = bias ? bias[col] : 0.f;
      #pragma unroll
      for (int i = 0; i < 2; ++i){
        #pragma unroll
        for (int r = 0; r < 4; ++r){
          int row = bm + wm + i*16 + lg*4 + r;
          C[(size_t)row*N + col] = acc[i][j][r] + bv;
        }
      }
    }
  }
}

// ---------- depthwise causal conv (D_CONV=4) + SiLU; writes f32 + bf16
__global__ __launch_bounds__(256) void k_conv_silu(const float* __restrict__ xr, const float* __restrict__ cw,
    const float* __restrict__ cb, float* __restrict__ xsc, unsigned short* __restrict__ xscb){
  int g = blockIdx.x*256 + threadIdx.x;   // d fastest, then l, then b
  int d = g & 511; int l = (g >> 9) & 1023; int b = g >> 19;
  float acc = cb[d];
  const float* w = cw + d*4;
  #pragma unroll
  for (int k=0;k<4;++k){
    int j = l + k - 3;
    if (j >= 0) acc = fmaf(w[k], xr[((size_t)(b*L + j))*(2*DI) + d], acc);
  }
  float v = acc * sigmoidf_(acc);
  xsc[g] = v; xscb[g] = f2bf(v);
}

// ---------- delta = softplus(x_dbl[:, :16] @ dt_w + dt_b)
__global__ __launch_bounds__(256) void k_dt_softplus(const float* __restrict__ xdbl, const float* __restrict__ dtw,
    const float* __restrict__ dtb, float* __restrict__ delta){
  int g = blockIdx.x*256 + threadIdx.x;   // n fastest; rows = NB*L
  int n = g & 511; int m = g >> 9;
  float acc = dtb[n];
  const float* xp = xdbl + (size_t)m*48;
  #pragma unroll
  for (int k=0;k<16;++k) acc = fmaf(xp[k], dtw[k*DI + n], acc);
  delta[g] = fmaxf(acc, 0.f) + log1pf(__expf(-fabsf(acc)));
}

// ---------- scan phase A: per-chunk local scan from h=0; store h_end and sum(delta)
__global__ __launch_bounds__(256) void k_scan_partial(const float* __restrict__ delta, const float* __restrict__ xsc,
    const float* __restrict__ xdbl, const float* __restrict__ A_log,
    float* __restrict__ hend, float* __restrict__ Ssum){
  int g = blockIdx.x*256 + threadIdx.x;   // d fastest, then chunk, then b
  int d = g & 511; int bc = g >> 9;       // bc = b*NC + c
  int c = bc & (NC-1); int b = bc >> 6;
  float A[DS];
  #pragma unroll
  for (int n=0;n<DS;++n) A[n] = -__expf(A_log[d*DS + n]);
  float h[DS];
  #pragma unroll
  for (int n=0;n<DS;++n) h[n] = 0.f;
  float S = 0.f;
  int l0 = c*CL;
  for (int t=0;t<CL;++t){
    size_t ix = (size_t)(b*L + l0 + t);
    float dlt = delta[ix*DI + d];
    float xv  = xsc[ix*DI + d];
    S += dlt;
    float dx = dlt * xv;
    const float* bp = xdbl + ix*48 + DR;
    #pragma unroll
    for (int n=0;n<DS;++n){
      float dA = __expf(dlt * A[n]);
      h[n] = fmaf(dA, h[n], dx * bp[n]);
    }
  }
  #pragma unroll
  for (int n=0;n<DS;++n) hend[((size_t)bc*DS + n)*DI + d] = h[n];
  Ssum[(size_t)bc*DI + d] = S;
}

// ---------- scan phase B: combine chunk states; thread = (b, n, d)
__global__ __launch_bounds__(256) void k_scan_combine(const float* __restrict__ hend, const float* __restrict__ Ssum,
    const float* __restrict__ A_log, float* __restrict__ hinit){
  int g = blockIdx.x*256 + threadIdx.x;   // d fastest, then n, then b : NB*DS*DI = 16384
  int d = g & 511; int n = (g >> 9) & 15; int b = g >> 13;
  float A = -__expf(A_log[d*DS + n]);
  float h = 0.f;
  for (int c=0;c<NC;++c){
    int bc = b*NC + c;
    hinit[((size_t)bc*DS + n)*DI + d] = h;
    float dec = __expf(A * Ssum[(size_t)bc*DI + d]);
    h = fmaf(dec, h, hend[((size_t)bc*DS + n)*DI + d]);
  }
}

// ---------- scan phase C: re-run chunk from correct h_init; fuse D-skip and SiLU gating; bf16 out
__global__ __launch_bounds__(256) void k_scan_final(const float* __restrict__ delta, const float* __restrict__ xsc,
    const float* __restrict__ xdbl, const float* __restrict__ xr, const float* __restrict__ A_log,
    const float* __restrict__ Dp, const float* __restrict__ hinit, unsigned short* __restrict__ ygb){
  int g = blockIdx.x*256 + threadIdx.x;
  int d = g & 511; int bc = g >> 9;
  int c = bc & (NC-1); int b = bc >> 6;
  float A[DS];
  #pragma unroll
  for (int n=0;n<DS;++n) A[n] = -__expf(A_log[d*DS + n]);
  float h[DS];
  #pragma unroll
  for (int n=0;n<DS;++n) h[n] = hinit[((size_t)bc*DS + n)*DI + d];
  float Dv = Dp[d];
  int l0 = c*CL;
  for (int t=0;t<CL;++t){
    size_t ix = (size_t)(b*L + l0 + t);
    float dlt = delta[ix*DI + d];
    float xv  = xsc[ix*DI + d];
    float res = xr[ix*(2*DI) + DI + d];
    float dx = dlt * xv;
    const float* bp = xdbl + ix*48 + DR;
    const float* cp = xdbl + ix*48 + DR + DS;
    float y = 0.f;
    #pragma unroll
    for (int n=0;n<DS;++n){
      float dA = __expf(dlt * A[n]);
      h[n] = fmaf(dA, h[n], dx * bp[n]);
      y = fmaf(h[n], cp[n], y);
    }
    y = fmaf(xv, Dv, y);
    ygb[ix*DI + d] = f2bf(y * (res * sigmoidf_(res)));
  }
}

// ---------- LayerNorm(mo) * w + b + residual
__global__ __launch_bounds__(256) void k_ln_add(const float* __restrict__ mo, const float* __restrict__ resid,
    const float* __restrict__ w, const float* __restrict__ bias, float* __restrict__ out){
  int row = blockIdx.x; int tid = threadIdx.x;
  float x = mo[(size_t)row*DM + tid];
  __shared__ float r1[256], r2[256];
  r1[tid] = x; r2[tid] = x*x;
  __syncthreads();
  for (int st=128; st>0; st>>=1){
    if (tid < st){ r1[tid]+=r1[tid+st]; r2[tid]+=r2[tid+st]; }
    __syncthreads();
  }
  float mu = r1[0] * (1.f/DM);
  float var = r2[0] * (1.f/DM) - mu*mu;
  float inv = rsqrtf(var + 1e-5f);
  out[(size_t)row*DM + tid] = resid[(size_t)row*DM + tid] + (x - mu)*inv*w[tid] + bias[tid];
}

static void run_block(const unsigned short* ub, const float* inb, const float* cw, const float* cb,
                      const float* dtw, const float* dtb, const float* Alog, const float* Dp, const float* ob,
                      const unsigned short* Wti, const unsigned short* Wtx, const unsigned short* Wto,
                      float* xr, float* xsc, unsigned short* xscb, float* xdbl, float* dlt,
                      unsigned short* ygb, float* hend, float* hinit, float* Ssum, float* mo,
                      hipStream_t stream){
  dim3 b256(256);
  k_gemm_mfma<<<dim3(16,32), b256, 0, stream>>>(ub, Wti, inb, xr, NB*L, 2*DI, DM);
  k_conv_silu<<<4096, b256, 0, stream>>>(xr, cw, cb, xsc, xscb);
  k_gemm_mfma<<<dim3(1,32), b256, 0, stream>>>(xscb, Wtx, nullptr, xdbl, NB*L, DR + 2*DS, DI);
  k_dt_softplus<<<4096, b256, 0, stream>>>(xdbl, dtw, dtb, dlt);
  k_scan_partial<<<NB*NC*DI/256, b256, 0, stream>>>(dlt, xsc, xdbl, Alog, hend, Ssum);
  k_scan_combine<<<NB*DS*DI/256, b256, 0, stream>>>(hend, Ssum, Alog, hinit);
  k_scan_final<<<NB*NC*DI/256, b256, 0, stream>>>(dlt, xsc, xdbl, xr, Alog, Dp, hinit, ygb);
  k_gemm_mfma<<<dim3(4,32), b256, 0, stream>>>(ygb, Wto, ob, mo, NB*L, DM, DI);
}

extern "C" void kernel_launch(void* const* d_in, const int* in_sizes, int n_in,
                              void* d_out, int out_size, void* d_ws, size_t ws_size,
                              hipStream_t stream) {
  const float* x    = (const float*)d_in[0];
  const float* ln1w = (const float*)d_in[1];
  const float* ln1b = (const float*)d_in[2];
  const float* ln2w = (const float*)d_in[3];
  const float* ln2b = (const float*)d_in[4];

  const float* m1[11]; const float* m2[11];
  for (int i=0;i<11;++i){ m1[i] = (const float*)d_in[5+i]; m2[i] = (const float*)d_in[16+i]; }
  // order: in_w, in_b, conv_w, conv_b, xproj_w, dt_w, dt_b, A_log, D, out_w, out_b

  float* ws = (float*)d_ws;
  float*          u0   = ws;                               // 524288
  unsigned short* u0b  = (unsigned short*)(ws + 524288);   // 262144 slots
  float*          xr   = ws + 786432;                      // 2097152
  float*          xsc  = ws + 2883584;                     // 1048576
  unsigned short* xscb = (unsigned short*)(ws + 3932160);  // 524288 slots
  float*          xdbl = ws + 4456448;                     // 98304
  float*          dlt  = ws + 4554752;                     // 1048576 (xt1 aliases)
  unsigned short* ygb  = (unsigned short*)(ws + 5603328);  // 524288 slots
  float*          hend = ws + 6127616;                     // 1048576 (mo aliases)
  float*          hinit= ws + 7176192;                     // 1048576
  float*          Ssum = ws + 8224768;                     // 65536
  float*          u2   = ws + 8290304;                     // 524288
  unsigned short* Wt1i = (unsigned short*)(ws + 8814592);  // 131072 slots
  unsigned short* Wt1x = (unsigned short*)(ws + 8945664);  // 16384
  unsigned short* Wt1o = (unsigned short*)(ws + 8962048);  // 65536
  unsigned short* Wt2i = (unsigned short*)(ws + 9027584);  // 131072
  unsigned short* Wt2x = (unsigned short*)(ws + 9158656);  // 16384
  unsigned short* Wt2o = (unsigned short*)(ws + 9175040);  // 65536
  // total 9240576 floats = 36.96 MB
  unsigned short* u2b = u0b;      // u0b dead after block1 in_proj
  float* xt1 = dlt;               // dlt dead after block1 scan_final
  float* mo  = hend;              // hend dead after scan_combine
  float* xt3 = u0;                // u0 dead after block1 ln_add

  dim3 b256(256);
  // weight transpose+bf16 (tiny)
  k_wconv<<<1024, b256, 0, stream>>>(m1[0], Wt1i, DM, 2*DI, 2*DI);
  k_wconv<<<128,  b256, 0, stream>>>(m1[4], Wt1x, DI, DR+2*DS, 64);
  k_wconv<<<512,  b256, 0, stream>>>(m1[9], Wt1o, DI, DM, DM);
  k_wconv<<<1024, b256, 0, stream>>>(m2[0], Wt2i, DM, 2*DI, 2*DI);
  k_wconv<<<128,  b256, 0, stream>>>(m2[4], Wt2x, DI, DR+2*DS, 64);
  k_wconv<<<512,  b256, 0, stream>>>(m2[9], Wt2o, DI, DM, DM);

  k_transpose_in<<<2048, b256, 0, stream>>>(x, u0, u0b);

  run_block(u0b, m1[1], m1[2], m1[3], m1[5], m1[6], m1[7], m1[8], m1[10],
            Wt1i, Wt1x, Wt1o, xr, xsc, xscb, xdbl, dlt, ygb, hend, hinit, Ssum, mo, stream);
  k_ln_add<<<2048, b256, 0, stream>>>(mo, u0, ln1w, ln1b, xt1);

  k_flip<<<2048, b256, 0, stream>>>(xt1, u2, u2b);

  run_block(u2b, m2[1], m2[2], m2[3], m2[5], m2[6], m2[7], m2[8], m2[10],
            Wt2i, Wt2x, Wt2o, xr, xsc, xscb, xdbl, dlt, ygb, hend, hinit, Ssum, mo, stream);
  k_ln_add<<<2048, b256, 0, stream>>>(mo, u2, ln2w, ln2b, xt3);

  k_final<<<2048, b256, 0, stream>>>(xt3, (float*)d_out);
}

// Round 3
// 155.563 us; speedup vs baseline: 2.7069x; 1.0932x over previous
//
#include <hip/hip_runtime.h>
#include <hip/hip_bf16.h>
#include <math.h>

#define L 1024
#define NB 2
#define DM 256
#define DI 512
#define DS 16
#define DR 16
#define NC 64
#define CL 16   // L / NC

typedef unsigned int u32;
typedef short s16x8 __attribute__((ext_vector_type(8)));
typedef float f32x4 __attribute__((ext_vector_type(4)));

__device__ __forceinline__ float sigmoidf_(float x){ return 1.f/(1.f+__expf(-x)); }

__device__ __forceinline__ unsigned short f2bf(float v){
  u32 x = __float_as_uint(v);
  u32 r = (x + 0x7fffu + ((x >> 16) & 1u)) >> 16;
  return (unsigned short)r;
}

__device__ __forceinline__ void gload_lds16(const void* g, void* l){
  __builtin_amdgcn_global_load_lds((const __attribute__((address_space(1))) u32*)g,
                                   (__attribute__((address_space(3))) u32*)l, 16, 0, 0);
}

__device__ __forceinline__ void wave_reduce2(float& a, float& b){
  #pragma unroll
  for (int m=32; m; m>>=1){ a += __shfl_xor(a, m, 64); b += __shfl_xor(b, m, 64); }
}

// ---------- weight prep: all transposes/bf16 conversions + fused dt weight.
// Per block p: Wti[1024][256], Wtx[576][512] (cols 0..511 = xproj[:, :16]@dtw, 512..543 = B/C, rest 0),
//              Wto[256][512].
#define SEG1 262144
#define SEG2 294912
#define SEG3 131072
#define SEGP (SEG1+SEG2+SEG3)
__global__ __launch_bounds__(256) void k_prep(
    const float* __restrict__ inw1, const float* __restrict__ xpw1, const float* __restrict__ dtw1, const float* __restrict__ outw1,
    const float* __restrict__ inw2, const float* __restrict__ xpw2, const float* __restrict__ dtw2, const float* __restrict__ outw2,
    unsigned short* __restrict__ Wt1i, unsigned short* __restrict__ Wt1x, unsigned short* __restrict__ Wt1o,
    unsigned short* __restrict__ Wt2i, unsigned short* __restrict__ Wt2x, unsigned short* __restrict__ Wt2o){
  int g = blockIdx.x*256 + threadIdx.x;
  int p = g >= SEGP;
  int r = g - p*SEGP;
  const float* inw = p ? inw2 : inw1;  const float* xpw = p ? xpw2 : xpw1;
  const float* dtw = p ? dtw2 : dtw1;  const float* outw = p ? outw2 : outw1;
  unsigned short* Wti = p ? Wt2i : Wt1i; unsigned short* Wtx = p ? Wt2x : Wt1x;
  unsigned short* Wto = p ? Wt2o : Wt1o;
  if (r < SEG1){
    int n = r >> 8, k = r & 255;
    Wti[r] = f2bf(inw[(size_t)k*1024 + n]);
  } else if (r < SEG1+SEG2){
    int q = r - SEG1; int n = q >> 9, k = q & 511;
    float v;
    if (n < 512){
      float acc = 0.f;
      #pragma unroll
      for (int j=0;j<16;++j) acc = fmaf(xpw[k*48 + j], dtw[j*512 + n], acc);
      v = acc;
    } else if (n < 544){
      v = xpw[k*48 + 16 + (n - 512)];
    } else v = 0.f;
    Wtx[q] = f2bf(v);
  } else {
    int q = r - SEG1 - SEG2; int n = q >> 9, k = q & 511;
    Wto[q] = f2bf(outw[(size_t)k*256 + n]);
  }
}

// ---------- transpose in: x (b,c,l) -> u (b,l,c) via LDS tile; f32 + bf16
__global__ __launch_bounds__(256) void k_transpose_in(const float* __restrict__ x,
    float* __restrict__ u, unsigned short* __restrict__ ub){
  __shared__ float T[64][65];
  int t = threadIdx.x;
  int bidx = blockIdx.x;                 // b*64 + ct*16 + lt
  int lt = bidx & 15, ct = (bidx >> 4) & 3, b = bidx >> 6;
  int l0 = lt*64, c0 = ct*64;
  int lsub = (t & 15)*4, csub = t >> 4;
  #pragma unroll
  for (int i=0;i<4;++i){
    int c = csub + i*16;
    float4 v = *(const float4*)(x + ((size_t)(b*256 + c0 + c))*1024 + l0 + lsub);
    T[lsub+0][c]=v.x; T[lsub+1][c]=v.y; T[lsub+2][c]=v.z; T[lsub+3][c]=v.w;
  }
  __syncthreads();
  int cw = (t & 15)*4, lw = t >> 4;
  #pragma unroll
  for (int i=0;i<4;++i){
    int l = lw + i*16;
    float4 v = make_float4(T[l][cw], T[l][cw+1], T[l][cw+2], T[l][cw+3]);
    size_t o = ((size_t)(b*1024 + l0 + l))*256 + c0 + cw;
    *(float4*)(u + o) = v;
    *(ushort4*)(ub + o) = make_ushort4(f2bf(v.x), f2bf(v.y), f2bf(v.z), f2bf(v.w));
  }
}

// ---------- MFMA bf16 GEMM: C[M][N] f32 = A[M][K]bf16 @ Wt[N][K]bf16^T (+bias)
__global__ __launch_bounds__(256) void k_gemm_mfma(const unsigned short* __restrict__ A,
    const unsigned short* __restrict__ Wt, const float* __restrict__ bias,
    float* __restrict__ C, int M, int N, int K){
  __shared__ __align__(16) unsigned short As[64*64];
  __shared__ __align__(16) unsigned short Bs[64*64];
  int tid = threadIdx.x;
  int lane = tid & 63;
  int wid  = tid >> 6;
  int bm = blockIdx.y * 64, bn = blockIdx.x * 64;
  int wm = (wid >> 1) * 32, wn = (wid & 1) * 32;
  int lrow = lane & 15, lg = lane >> 4;
  int srow = tid >> 3;
  int ssl  = tid & 7;
  int sswz = ssl ^ (srow & 7);

  f32x4 acc[2][2] = {};

  for (int k0 = 0; k0 < K; k0 += 64){
    #pragma unroll
    for (int i = 0; i < 2; ++i){
      int row = srow + i*32;
      gload_lds16(A  + (size_t)(bm + row)*K + k0 + sswz*8, &As[row*64 + ssl*8]);
      gload_lds16(Wt + (size_t)(bn + row)*K + k0 + sswz*8, &Bs[row*64 + ssl*8]);
    }
    __syncthreads();
    #pragma unroll
    for (int ks = 0; ks < 2; ++ks){
      int kg = ks*4 + lg;
      int swz = (kg ^ (lrow & 7)) << 3;
      s16x8 a[2], b[2];
      #pragma unroll
      for (int f = 0; f < 2; ++f){
        a[f] = *(const s16x8*)&As[(wm + f*16 + lrow)*64 + swz];
        b[f] = *(const s16x8*)&Bs[(wn + f*16 + lrow)*64 + swz];
      }
      #pragma unroll
      for (int i = 0; i < 2; ++i)
        #pragma unroll
        for (int j = 0; j < 2; ++j)
          acc[i][j] = __builtin_amdgcn_mfma_f32_16x16x32_bf16(a[i], b[j], acc[i][j], 0, 0, 0);
    }
    __syncthreads();
  }
  #pragma unroll
  for (int j = 0; j < 2; ++j){
    int col = bn + wn + j*16 + lrow;
    if (col < N){
      float bv = bias ? bias[col] : 0.f;
      #pragma unroll
      for (int i = 0; i < 2; ++i){
        #pragma unroll
        for (int r = 0; r < 4; ++r){
          int row = bm + wm + i*16 + lg*4 + r;
          C[(size_t)row*N + col] = acc[i][j][r] + bv;
        }
      }
    }
  }
}

// ---------- fused xproj GEMM: A[M][512]bf16 @ Wtx[576][512]^T.
// cols 0..511 -> delta = softplus(acc + dtb); cols 512..543 -> BC[row][col-512].
__global__ __launch_bounds__(256) void k_gemm_xproj(const unsigned short* __restrict__ A,
    const unsigned short* __restrict__ Wt, const float* __restrict__ dtb,
    float* __restrict__ dlt, float* __restrict__ BC, int M){
  const int K = 512;
  __shared__ __align__(16) unsigned short As[64*64];
  __shared__ __align__(16) unsigned short Bs[64*64];
  int tid = threadIdx.x;
  int lane = tid & 63;
  int wid  = tid >> 6;
  int bm = blockIdx.y * 64, bn = blockIdx.x * 64;
  int wm = (wid >> 1) * 32, wn = (wid & 1) * 32;
  int lrow = lane & 15, lg = lane >> 4;
  int srow = tid >> 3;
  int ssl  = tid & 7;
  int sswz = ssl ^ (srow & 7);

  f32x4 acc[2][2] = {};

  for (int k0 = 0; k0 < K; k0 += 64){
    #pragma unroll
    for (int i = 0; i < 2; ++i){
      int row = srow + i*32;
      gload_lds16(A  + (size_t)(bm + row)*K + k0 + sswz*8, &As[row*64 + ssl*8]);
      gload_lds16(Wt + (size_t)(bn + row)*K + k0 + sswz*8, &Bs[row*64 + ssl*8]);
    }
    __syncthreads();
    #pragma unroll
    for (int ks = 0; ks < 2; ++ks){
      int kg = ks*4 + lg;
      int swz = (kg ^ (lrow & 7)) << 3;
      s16x8 a[2], b[2];
      #pragma unroll
      for (int f = 0; f < 2; ++f){
        a[f] = *(const s16x8*)&As[(wm + f*16 + lrow)*64 + swz];
        b[f] = *(const s16x8*)&Bs[(wn + f*16 + lrow)*64 + swz];
      }
      #pragma unroll
      for (int i = 0; i < 2; ++i)
        #pragma unroll
        for (int j = 0; j < 2; ++j)
          acc[i][j] = __builtin_amdgcn_mfma_f32_16x16x32_bf16(a[i], b[j], acc[i][j], 0, 0, 0);
    }
    __syncthreads();
  }
  #pragma unroll
  for (int j = 0; j < 2; ++j){
    int col = bn + wn + j*16 + lrow;
    if (col < 512){
      float bv = dtb[col];
      #pragma unroll
      for (int i = 0; i < 2; ++i){
        #pragma unroll
        for (int r = 0; r < 4; ++r){
          int row = bm + wm + i*16 + lg*4 + r;
          float a = acc[i][j][r] + bv;
          dlt[(size_t)row*512 + col] = fmaxf(a, 0.f) + log1pf(__expf(-fabsf(a)));
        }
      }
    } else if (col < 544){
      #pragma unroll
      for (int i = 0; i < 2; ++i){
        #pragma unroll
        for (int r = 0; r < 4; ++r){
          int row = bm + wm + i*16 + lg*4 + r;
          BC[(size_t)row*32 + (col - 512)] = acc[i][j][r];
        }
      }
    }
  }
}

// ---------- depthwise causal conv (D_CONV=4) + SiLU; writes f32 + bf16
__global__ __launch_bounds__(256) void k_conv_silu(const float* __restrict__ xr, const float* __restrict__ cw,
    const float* __restrict__ cb, float* __restrict__ xsc, unsigned short* __restrict__ xscb){
  int g = blockIdx.x*256 + threadIdx.x;   // d fastest, then l, then b
  int d = g & 511; int l = (g >> 9) & 1023; int b = g >> 19;
  float acc = cb[d];
  const float* w = cw + d*4;
  #pragma unroll
  for (int k=0;k<4;++k){
    int j = l + k - 3;
    if (j >= 0) acc = fmaf(w[k], xr[((size_t)(b*L + j))*(2*DI) + d], acc);
  }
  float v = acc * sigmoidf_(acc);
  xsc[g] = v; xscb[g] = f2bf(v);
}

// ---------- scan phase A: per-chunk local scan from h=0; store h_end and sum(delta)
__global__ __launch_bounds__(256) void k_scan_partial(const float* __restrict__ delta, const float* __restrict__ xsc,
    const float* __restrict__ BC, const float* __restrict__ A_log,
    float* __restrict__ hend, float* __restrict__ Ssum){
  int g = blockIdx.x*256 + threadIdx.x;   // d fastest, then chunk, then b
  int d = g & 511; int bc = g >> 9;
  int c = bc & (NC-1); int b = bc >> 6;
  float A[DS];
  #pragma unroll
  for (int n=0;n<DS;++n) A[n] = -__expf(A_log[d*DS + n]);
  float h[DS];
  #pragma unroll
  for (int n=0;n<DS;++n) h[n] = 0.f;
  float S = 0.f;
  int l0 = c*CL;
  for (int t=0;t<CL;++t){
    size_t ix = (size_t)(b*L + l0 + t);
    float dlt = delta[ix*DI + d];
    float xv  = xsc[ix*DI + d];
    S += dlt;
    float dx = dlt * xv;
    const float* bp = BC + ix*32;
    #pragma unroll
    for (int n=0;n<DS;++n){
      float dA = __expf(dlt * A[n]);
      h[n] = fmaf(dA, h[n], dx * bp[n]);
    }
  }
  #pragma unroll
  for (int n=0;n<DS;++n) hend[((size_t)bc*DS + n)*DI + d] = h[n];
  Ssum[(size_t)bc*DI + d] = S;
}

// ---------- scan phase B: combine chunk states; thread = (b, n, d)
__global__ __launch_bounds__(256) void k_scan_combine(const float* __restrict__ hend, const float* __restrict__ Ssum,
    const float* __restrict__ A_log, float* __restrict__ hinit){
  int g = blockIdx.x*256 + threadIdx.x;   // NB*DS*DI = 16384
  int d = g & 511; int n = (g >> 9) & 15; int b = g >> 13;
  float A = -__expf(A_log[d*DS + n]);
  float h = 0.f;
  for (int c=0;c<NC;++c){
    int bc = b*NC + c;
    hinit[((size_t)bc*DS + n)*DI + d] = h;
    float dec = __expf(A * Ssum[(size_t)bc*DI + d]);
    h = fmaf(dec, h, hend[((size_t)bc*DS + n)*DI + d]);
  }
}

// ---------- scan phase C: re-run chunk from h_init; fuse D-skip and SiLU gating; bf16 out
__global__ __launch_bounds__(256) void k_scan_final(const float* __restrict__ delta, const float* __restrict__ xsc,
    const float* __restrict__ BC, const float* __restrict__ xr, const float* __restrict__ A_log,
    const float* __restrict__ Dp, const float* __restrict__ hinit, unsigned short* __restrict__ ygb){
  int g = blockIdx.x*256 + threadIdx.x;
  int d = g & 511; int bc = g >> 9;
  int c = bc & (NC-1); int b = bc >> 6;
  float A[DS];
  #pragma unroll
  for (int n=0;n<DS;++n) A[n] = -__expf(A_log[d*DS + n]);
  float h[DS];
  #pragma unroll
  for (int n=0;n<DS;++n) h[n] = hinit[((size_t)bc*DS + n)*DI + d];
  float Dv = Dp[d];
  int l0 = c*CL;
  for (int t=0;t<CL;++t){
    size_t ix = (size_t)(b*L + l0 + t);
    float dlt = delta[ix*DI + d];
    float xv  = xsc[ix*DI + d];
    float res = xr[ix*(2*DI) + DI + d];
    float dx = dlt * xv;
    const float* bp = BC + ix*32;
    const float* cp = bp + 16;
    float y = 0.f;
    #pragma unroll
    for (int n=0;n<DS;++n){
      float dA = __expf(dlt * A[n]);
      h[n] = fmaf(dA, h[n], dx * bp[n]);
      y = fmaf(h[n], cp[n], y);
    }
    y = fmaf(xv, Dv, y);
    ygb[ix*DI + d] = f2bf(y * (res * sigmoidf_(res)));
  }
}

// ---------- LN1 + residual + channel-flip; writes u2 f32 + bf16 (one wave per row)
__global__ __launch_bounds__(256) void k_ln_flip(const float* __restrict__ mo, const float* __restrict__ resid,
    const float* __restrict__ w, const float* __restrict__ bias,
    float* __restrict__ u2, unsigned short* __restrict__ u2b){
  int row = blockIdx.x*4 + (threadIdx.x >> 6);
  int lane = threadIdx.x & 63;
  int c4 = lane*4;
  float4 xv = *(const float4*)(mo + (size_t)row*256 + c4);
  float s1 = xv.x+xv.y+xv.z+xv.w;
  float s2 = xv.x*xv.x+xv.y*xv.y+xv.z*xv.z+xv.w*xv.w;
  wave_reduce2(s1, s2);
  float mu = s1*(1.f/256), var = s2*(1.f/256) - mu*mu;
  float inv = rsqrtf(var + 1e-5f);
  float4 rv = *(const float4*)(resid + (size_t)row*256 + c4);
  float4 wv = *(const float4*)(w + c4);
  float4 bv = *(const float4*)(bias + c4);
  float o0 = rv.x + (xv.x-mu)*inv*wv.x + bv.x;
  float o1 = rv.y + (xv.y-mu)*inv*wv.y + bv.y;
  float o2 = rv.z + (xv.z-mu)*inv*wv.z + bv.z;
  float o3 = rv.w + (xv.w-mu)*inv*wv.w + bv.w;
  size_t o = (size_t)row*256 + (252 - c4);
  *(float4*)(u2 + o) = make_float4(o3, o2, o1, o0);
  *(ushort4*)(u2b + o) = make_ushort4(f2bf(o3), f2bf(o2), f2bf(o1), f2bf(o0));
}

// ---------- LN2 + residual + flip + transpose-out: out[b,c,l] = val[b,l,255-c]
__global__ __launch_bounds__(256) void k_ln_out(const float* __restrict__ mo, const float* __restrict__ resid,
    const float* __restrict__ w, const float* __restrict__ bias, float* __restrict__ out){
  int row = blockIdx.x*4 + (threadIdx.x >> 6);
  int lane = threadIdx.x & 63;
  int c4 = lane*4;
  int b = row >> 10, l = row & 1023;
  float4 xv = *(const float4*)(mo + (size_t)row*256 + c4);
  float s1 = xv.x+xv.y+xv.z+xv.w;
  float s2 = xv.x*xv.x+xv.y*xv.y+xv.z*xv.z+xv.w*xv.w;
  wave_reduce2(s1, s2);
  float mu = s1*(1.f/256), var = s2*(1.f/256) - mu*mu;
  float inv = rsqrtf(var + 1e-5f);
  float4 rv = *(const float4*)(resid + (size_t)row*256 + c4);
  float4 wv = *(const float4*)(w + c4);
  float4 bv = *(const float4*)(bias + c4);
  float o0 = rv.x + (xv.x-mu)*inv*wv.x + bv.x;
  float o1 = rv.y + (xv.y-mu)*inv*wv.y + bv.y;
  float o2 = rv.z + (xv.z-mu)*inv*wv.z + bv.z;
  float o3 = rv.w + (xv.w-mu)*inv*wv.w + bv.w;
  size_t base = ((size_t)b*256 + 255) << 10;   // out[b][255-c][l]
  out[base - ((size_t)(c4+0) << 10) + l] = o0;
  out[base - ((size_t)(c4+1) << 10) + l] = o1;
  out[base - ((size_t)(c4+2) << 10) + l] = o2;
  out[base - ((size_t)(c4+3) << 10) + l] = o3;
}

static void run_block(const unsigned short* ub, const float* inb, const float* cw, const float* cb,
                      const float* dtb, const float* Alog, const float* Dp, const float* ob,
                      const unsigned short* Wti, const unsigned short* Wtx, const unsigned short* Wto,
                      float* xr, float* xsc, unsigned short* xscb, float* dlt, float* BC,
                      unsigned short* ygb, float* hend, float* hinit, float* Ssum, float* mo,
                      hipStream_t stream){
  dim3 b256(256);
  k_gemm_mfma<<<dim3(16,32), b256, 0, stream>>>(ub, Wti, inb, xr, NB*L, 2*DI, DM);
  k_conv_silu<<<4096, b256, 0, stream>>>(xr, cw, cb, xsc, xscb);
  k_gemm_xproj<<<dim3(9,32), b256, 0, stream>>>(xscb, Wtx, dtb, dlt, BC, NB*L);
  k_scan_partial<<<NB*NC*DI/256, b256, 0, stream>>>(dlt, xsc, BC, Alog, hend, Ssum);
  k_scan_combine<<<NB*DS*DI/256, b256, 0, stream>>>(hend, Ssum, Alog, hinit);
  k_scan_final<<<NB*NC*DI/256, b256, 0, stream>>>(dlt, xsc, BC, xr, Alog, Dp, hinit, ygb);
  k_gemm_mfma<<<dim3(4,32), b256, 0, stream>>>(ygb, Wto, ob, mo, NB*L, DM, DI);
}

extern "C" void kernel_launch(void* const* d_in, const int* in_sizes, int n_in,
                              void* d_out, int out_size, void* d_ws, size_t ws_size,
                              hipStream_t stream) {
  const float* x    = (const float*)d_in[0];
  const float* ln1w = (const float*)d_in[1];
  const float* ln1b = (const float*)d_in[2];
  const float* ln2w = (const float*)d_in[3];
  const float* ln2b = (const float*)d_in[4];

  const float* m1[11]; const float* m2[11];
  for (int i=0;i<11;++i){ m1[i] = (const float*)d_in[5+i]; m2[i] = (const float*)d_in[16+i]; }
  // order: in_w, in_b, conv_w, conv_b, xproj_w, dt_w, dt_b, A_log, D, out_w, out_b

  float* ws = (float*)d_ws;
  float*          u0   = ws;                               // 524288
  unsigned short* u0b  = (unsigned short*)(ws + 524288);   // 131072 fl
  float*          xr   = ws + 655360;                      // 2097152
  float*          xsc  = ws + 2752512;                     // 1048576
  unsigned short* xscb = (unsigned short*)(ws + 3801088);  // 262144 fl
  float*          dlt  = ws + 4063232;                     // 1048576
  float*          BC   = ws + 5111808;                     // 65536
  unsigned short* ygb  = (unsigned short*)(ws + 5177344);  // 262144 fl
  float*          hend = ws + 5439488;                     // 1048576
  float*          hinit= ws + 6488064;                     // 1048576
  float*          Ssum = ws + 7536640;                     // 65536
  float*          u2   = ws + 7602176;                     // 524288
  unsigned short* Wt1i = (unsigned short*)(ws + 8126464);  // 131072 fl
  unsigned short* Wt1x = (unsigned short*)(ws + 8257536);  // 147456 fl
  unsigned short* Wt1o = (unsigned short*)(ws + 8404992);  // 65536 fl
  unsigned short* Wt2i = (unsigned short*)(ws + 8470528);  // 131072 fl
  unsigned short* Wt2x = (unsigned short*)(ws + 8601600);  // 147456 fl
  unsigned short* Wt2o = (unsigned short*)(ws + 8749056);  // 65536 fl
  // total 8814592 floats = 35.26 MB
  unsigned short* u2b = u0b;      // dead after block1 in_proj
  float* mo = hend;               // hend dead after scan_combine

  dim3 b256(256);
  k_prep<<<2*SEGP/256, b256, 0, stream>>>(m1[0], m1[4], m1[5], m1[9],
                                          m2[0], m2[4], m2[5], m2[9],
                                          Wt1i, Wt1x, Wt1o, Wt2i, Wt2x, Wt2o);
  k_transpose_in<<<128, b256, 0, stream>>>(x, u0, u0b);

  run_block(u0b, m1[1], m1[2], m1[3], m1[6], m1[7], m1[8], m1[10],
            Wt1i, Wt1x, Wt1o, xr, xsc, xscb, dlt, BC, ygb, hend, hinit, Ssum, mo, stream);
  k_ln_flip<<<512, b256, 0, stream>>>(mo, u0, ln1w, ln1b, u2, u2b);

  run_block(u2b, m2[1], m2[2], m2[3], m2[6], m2[7], m2[8], m2[10],
            Wt2i, Wt2x, Wt2o, xr, xsc, xscb, dlt, BC, ygb, hend, hinit, Ssum, mo, stream);
  k_ln_out<<<512, b256, 0, stream>>>(mo, u2, ln2w, ln2b, (float*)d_out);
}